// Round 4
// baseline (710.507 us; speedup 1.0000x reference)
//
#include <hip/hip_runtime.h>
#include <stdint.h>

typedef unsigned short u16;
typedef unsigned int   u32;
typedef __bf16 bf16x8_t __attribute__((ext_vector_type(8)));
typedef float  f32x4_t  __attribute__((ext_vector_type(4)));

#define MFMA16(a, b, c) __builtin_amdgcn_mfma_f32_16x16x32_bf16((a), (b), (c), 0, 0, 0)

__device__ __forceinline__ float bf2f(u16 u) {
    union { u32 i; float f; } c; c.i = ((u32)u) << 16; return c.f;
}
__device__ __forceinline__ u16 f2bf(float f) {
    union { float f; u32 i; } c; c.f = f;
    u32 x = c.i;
    return (u16)((x + 0x7fffu + ((x >> 16) & 1u)) >> 16);  // RNE
}

// ---------------------------------------------------------------------------
// Kernel D: detect input dtype. Even-indexed u16s of an fp32 buffer are raw
// mantissa halves (uniform bits -> ~32% sane exponent fields); of a bf16
// buffer they are real values (~100% sane). flag = 1 -> inputs are fp32.
// ---------------------------------------------------------------------------
__global__ __launch_bounds__(64) void detect_k(const u16* __restrict__ xu,
                                               u32* __restrict__ flag) {
    __shared__ int cnt;
    if (threadIdx.x == 0) cnt = 0;
    __syncthreads();
    int local = 0;
#pragma unroll
    for (int j = 0; j < 4; j++) {
        int i = threadIdx.x * 4 + j;        // 256 samples
        u16 w = xu[2 * i];                  // even u16 halves
        int e = (w >> 7) & 0xff;
        if (e >= 80 && e <= 160) local++;   // sane bf16 exponent for ~N(0,1)
    }
    atomicAdd(&cnt, local);
    __syncthreads();
    if (threadIdx.x == 0) *flag = (cnt < 160) ? 1u : 0u;
}

// ---------------------------------------------------------------------------
// Kernel W: convert W1/b1/W2/b2 to bf16 copies in workspace (either dtype).
// Total elements: 196608 + 768 + 65536 + 256 = 263168 = 1028 * 256.
// ---------------------------------------------------------------------------
__global__ __launch_bounds__(256) void conv_w(const void* __restrict__ W1,
                                              const void* __restrict__ b1,
                                              const void* __restrict__ W2,
                                              const void* __restrict__ b2,
                                              const u32* __restrict__ flag,
                                              u16* __restrict__ W1b,
                                              u16* __restrict__ b1b,
                                              u16* __restrict__ W2b,
                                              u16* __restrict__ b2b) {
    int i = blockIdx.x * 256 + threadIdx.x;
    const int n1 = 196608, n2 = 768, n3 = 65536;
    const void* src; u16* dst; int li;
    if (i < n1)                { src = W1; dst = W1b; li = i; }
    else if (i < n1 + n2)      { src = b1; dst = b1b; li = i - n1; }
    else if (i < n1 + n2 + n3) { src = W2; dst = W2b; li = i - n1 - n2; }
    else                       { src = b2; dst = b2b; li = i - n1 - n2 - n3; }
    u16 v;
    if (*flag) v = f2bf(((const float*)src)[li]);
    else       v = ((const u16*)src)[li];
    dst[li] = v;
}

// ---------------------------------------------------------------------------
// Kernel X: x [b][c][hw] (fp32 or bf16) -> xT [b*4096+hw][c] bf16 (pixel-major)
// ---------------------------------------------------------------------------
__global__ __launch_bounds__(256) void conv_x(const void* __restrict__ X,
                                              const u32* __restrict__ flag,
                                              u16* __restrict__ XT) {
    __shared__ __align__(16) u16 tile[64][68];
    const int b = blockIdx.z, c0 = blockIdx.y * 64, h0 = blockIdx.x * 64;
    const int tid = threadIdx.x;
    const int col = tid & 63, rq = tid >> 6;
    if (*flag) {
        const float* Xf = (const float*)X;
#pragma unroll
        for (int i = 0; i < 16; i++) {
            int row = i * 4 + rq;
            tile[row][col] = f2bf(Xf[((size_t)(b * 256 + c0 + row)) * 4096 + h0 + col]);
        }
    } else {
        const u16* Xh = (const u16*)X;
#pragma unroll
        for (int i = 0; i < 16; i++) {
            int row = i * 4 + rq;
            tile[row][col] = Xh[((size_t)(b * 256 + c0 + row)) * 4096 + h0 + col];
        }
    }
    __syncthreads();
#pragma unroll
    for (int i = 0; i < 16; i++) {
        int row = i * 4 + rq;  // hw-local
        XT[((size_t)(b * 4096 + h0 + row)) * 256 + c0 + col] = tile[col][row];
    }
}

// ---------------------------------------------------------------------------
// Shared GEMM mainloop: C[128x128] += A[128xK] * B[128xK]^T (both k-contig).
// LDS XOR swizzle: chunk (row, c) stored at row*64 + ((c ^ (row&7))*8).
// ---------------------------------------------------------------------------
__device__ __forceinline__ void gemm_loop(const u16* __restrict__ A,
                                          const u16* __restrict__ B,
                                          int K, int bm, int bn,
                                          u16* sA, u16* sB, f32x4_t acc[4][4]) {
    const int tid  = threadIdx.x;
    const int lane = tid & 63, wave = tid >> 6;
    const int quad = lane >> 4, l16 = lane & 15;
    const int wm = (wave >> 1) * 64, wn = (wave & 1) * 64;

    for (int kt = 0; kt < K; kt += 64) {
        __syncthreads();
        uint4 av[4], bv[4];
#pragma unroll
        for (int i = 0; i < 4; i++) {
            int idx = i * 256 + tid;
            int row = idx >> 3, cp = idx & 7;
            av[i] = *(const uint4*)(A + ((size_t)(bm * 128 + row)) * K + kt + cp * 8);
            bv[i] = *(const uint4*)(B + ((size_t)(bn * 128 + row)) * K + kt + cp * 8);
        }
#pragma unroll
        for (int i = 0; i < 4; i++) {
            int idx = i * 256 + tid;
            int row = idx >> 3, cp = idx & 7;
            int sp = row * 64 + ((cp ^ (row & 7)) * 8);
            *(uint4*)(sA + sp) = av[i];
            *(uint4*)(sB + sp) = bv[i];
        }
        __syncthreads();
#pragma unroll
        for (int ks = 0; ks < 2; ks++) {
            bf16x8_t af[4], bg[4];
#pragma unroll
            for (int i = 0; i < 4; i++) {
                int row = wm + i * 16 + l16;
                int cp = (ks * 4 + quad) ^ (row & 7);
                af[i] = *(const bf16x8_t*)(sA + row * 64 + cp * 8);
            }
#pragma unroll
            for (int j = 0; j < 4; j++) {
                int row = wn + j * 16 + l16;
                int cp = (ks * 4 + quad) ^ (row & 7);
                bg[j] = *(const bf16x8_t*)(sB + row * 64 + cp * 8);
            }
#pragma unroll
            for (int i = 0; i < 4; i++)
#pragma unroll
                for (int j = 0; j < 4; j++)
                    acc[i][j] = MFMA16(af[i], bg[j], acc[i][j]);
        }
    }
}

// ---------------------------------------------------------------------------
// Kernel 1: qkv = xT @ W1^T + b1, deinterleaved into planar Q/K/V [b][c][hw]
// ---------------------------------------------------------------------------
__global__ __launch_bounds__(256) void gemm_qkv(const u16* __restrict__ XT,
                                                const u16* __restrict__ W1,
                                                const u16* __restrict__ b1,
                                                u16* __restrict__ Qp,
                                                u16* __restrict__ Kp,
                                                u16* __restrict__ Vp) {
    __shared__ __align__(16) u16 sA[128 * 64];
    __shared__ __align__(16) u16 sB[128 * 64];
    f32x4_t acc[4][4];
    const f32x4_t zz = {0.f, 0.f, 0.f, 0.f};
#pragma unroll
    for (int i = 0; i < 4; i++)
#pragma unroll
        for (int j = 0; j < 4; j++) acc[i][j] = zz;

    const int bm = blockIdx.x, bn = blockIdx.y;
    gemm_loop(XT, W1, 256, bm, bn, sA, sB, acc);

    const int lane = threadIdx.x & 63, wave = threadIdx.x >> 6;
    const int quad = lane >> 4, l16 = lane & 15;
    const int wm = (wave >> 1) * 64, wn = (wave & 1) * 64;
    const int b = bm >> 5;
    const int hw0 = (bm & 31) * 128;
#pragma unroll
    for (int j = 0; j < 4; j++) {
        int o = bn * 128 + wn + j * 16 + l16;
        float bias = bf2f(b1[o]);
        int which = o % 3, c = o / 3;
        u16* dst = (which == 0) ? Qp : (which == 1) ? Kp : Vp;
        size_t base = ((size_t)(b * 256 + c)) * 4096;
#pragma unroll
        for (int i = 0; i < 4; i++) {
            int m0 = hw0 + wm + i * 16 + quad * 4;  // 4 contiguous hw
            u32 lo = (u32)f2bf(acc[i][j][0] + bias) | ((u32)f2bf(acc[i][j][1] + bias) << 16);
            u32 hi = (u32)f2bf(acc[i][j][2] + bias) | ((u32)f2bf(acc[i][j][3] + bias) << 16);
            u32* d32 = (u32*)(dst + base + m0);
            d32[0] = lo; d32[1] = hi;
        }
    }
}

// ---------------------------------------------------------------------------
// Kernel 2: windowed overlapping attention (Q 8x8, K/V 12x12 zero-padded).
// Output pixel-major [b*4096+hw][c], c = head*32 + e.
// ---------------------------------------------------------------------------
__global__ __launch_bounds__(256) void attn_kernel(const u16* __restrict__ Qp,
                                                   const u16* __restrict__ Kp,
                                                   const u16* __restrict__ Vp,
                                                   u16* __restrict__ Op) {
    __shared__ __align__(16) u16 Qs[64 * 40];    // [q][e]   stride 40
    __shared__ __align__(16) u16 Ks[144 * 40];   // [k][e]   stride 40
    __shared__ __align__(16) u16 Vt[32 * 168];   // [e][k]   stride 168, cols 144..159 zero
    __shared__ __align__(16) u16 Ps[64 * 168];   // [q][k]   stride 168, cols 144..159 zero

    const int tid  = threadIdx.x;
    const int lane = tid & 63, wave = tid >> 6;
    const int quad = lane >> 4, l16 = lane & 15;
    const int win = blockIdx.x, head = blockIdx.y, b = blockIdx.z;
    const int wi = win >> 3, wj = win & 7;
    const size_t cb = ((size_t)(b * 256 + head * 32)) * 4096;

    for (int t = tid; t < 64 * 16; t += 256) Ps[(t >> 4) * 168 + 144 + (t & 15)] = 0;
    for (int t = tid; t < 32 * 16; t += 256) Vt[(t >> 4) * 168 + 144 + (t & 15)] = 0;

    {
        int qy = tid & 7, e = tid >> 3;
        const u16* src = Qp + cb + (size_t)e * 4096 + ((wi * 8 + qy) * 64 + wj * 8);
        uint4 v = *(const uint4*)src;
        int qb = qy * 8;
        Qs[(qb + 0) * 40 + e] = (u16)(v.x & 0xffff);
        Qs[(qb + 1) * 40 + e] = (u16)(v.x >> 16);
        Qs[(qb + 2) * 40 + e] = (u16)(v.y & 0xffff);
        Qs[(qb + 3) * 40 + e] = (u16)(v.y >> 16);
        Qs[(qb + 4) * 40 + e] = (u16)(v.z & 0xffff);
        Qs[(qb + 5) * 40 + e] = (u16)(v.z >> 16);
        Qs[(qb + 6) * 40 + e] = (u16)(v.w & 0xffff);
        Qs[(qb + 7) * 40 + e] = (u16)(v.w >> 16);
    }
    for (int t = tid; t < 384; t += 256) {
        int e = t & 31, ky = t >> 5;
        int gy = wi * 8 - 2 + ky;
        bool rowok = (gy >= 0) && (gy < 64);
        const u16* kr = Kp + cb + (size_t)e * 4096 + gy * 64;
        const u16* vr = Vp + cb + (size_t)e * 4096 + gy * 64;
        int krow = ky * 12;
#pragma unroll
        for (int kx = 0; kx < 12; kx++) {
            int gx = wj * 8 - 2 + kx;
            bool ok = rowok && (gx >= 0) && (gx < 64);
            u16 kv = ok ? kr[gx] : (u16)0;
            u16 vv = ok ? vr[gx] : (u16)0;
            Ks[(krow + kx) * 40 + e] = kv;
            Vt[e * 168 + krow + kx] = vv;
        }
    }
    __syncthreads();

    const float scale = 0.17677669529663687f;  // 1/sqrt(32)
    float s[9][4];
    {
        bf16x8_t aF = *(const bf16x8_t*)(Qs + (wave * 16 + l16) * 40 + quad * 8);
        const f32x4_t zz = {0.f, 0.f, 0.f, 0.f};
#pragma unroll
        for (int j = 0; j < 9; j++) {
            bf16x8_t bF = *(const bf16x8_t*)(Ks + (j * 16 + l16) * 40 + quad * 8);
            f32x4_t d = MFMA16(aF, bF, zz);
#pragma unroll
            for (int r = 0; r < 4; r++) s[j][r] = d[r] * scale;
        }
    }
    float mx[4] = {-1e30f, -1e30f, -1e30f, -1e30f};
#pragma unroll
    for (int j = 0; j < 9; j++)
#pragma unroll
        for (int r = 0; r < 4; r++) mx[r] = fmaxf(mx[r], s[j][r]);
#pragma unroll
    for (int off = 1; off < 16; off <<= 1)
#pragma unroll
        for (int r = 0; r < 4; r++) mx[r] = fmaxf(mx[r], __shfl_xor(mx[r], off, 16));

    float sm[4] = {0.f, 0.f, 0.f, 0.f};
#pragma unroll
    for (int j = 0; j < 9; j++) {
#pragma unroll
        for (int r = 0; r < 4; r++) {
            float p = __expf(fminf(s[j][r] - mx[r], 0.f));
            u16 pb = f2bf(p);
            sm[r] += bf2f(pb);
            Ps[(wave * 16 + quad * 4 + r) * 168 + j * 16 + l16] = pb;
        }
    }
#pragma unroll
    for (int off = 1; off < 16; off <<= 1)
#pragma unroll
        for (int r = 0; r < 4; r++) sm[r] += __shfl_xor(sm[r], off, 16);

    __syncthreads();  // fence Ps u16 stores vs bf16x8 loads

    f32x4_t oa[2];
    oa[0] = (f32x4_t){0.f, 0.f, 0.f, 0.f};
    oa[1] = (f32x4_t){0.f, 0.f, 0.f, 0.f};
#pragma unroll
    for (int kk = 0; kk < 5; kk++) {
        bf16x8_t aP = *(const bf16x8_t*)(Ps + (wave * 16 + l16) * 168 + kk * 32 + quad * 8);
#pragma unroll
        for (int nt = 0; nt < 2; nt++) {
            bf16x8_t bV = *(const bf16x8_t*)(Vt + (nt * 16 + l16) * 168 + kk * 32 + quad * 8);
            oa[nt] = MFMA16(aP, bV, oa[nt]);
        }
    }
    float inv[4];
#pragma unroll
    for (int r = 0; r < 4; r++) inv[r] = 1.0f / fmaxf(sm[r], 1e-20f);
#pragma unroll
    for (int nt = 0; nt < 2; nt++) {
        int e = nt * 16 + l16;
#pragma unroll
        for (int r = 0; r < 4; r++) {
            int q = wave * 16 + quad * 4 + r;
            int qy = q >> 3, qx = q & 7;
            size_t pix = (size_t)(b * 4096) + (wi * 8 + qy) * 64 + (wj * 8 + qx);
            Op[pix * 256 + head * 32 + e] = f2bf(oa[nt][r] * inv[r]);
        }
    }
}

// ---------------------------------------------------------------------------
// Kernel 3: y = attn @ W2^T + b2 -> d_out [b][c'][hw]; dtype per flag.
// flag==1 (fp32 inputs) -> FP32 output (reference output dtype follows input).
// flag==0 (bf16 inputs) -> bf16 output.
// ---------------------------------------------------------------------------
__global__ __launch_bounds__(256) void gemm_out(const u16* __restrict__ Ap,
                                                const u16* __restrict__ W2,
                                                const u16* __restrict__ b2,
                                                const u32* __restrict__ flag,
                                                void* __restrict__ Y) {
    __shared__ __align__(16) u16 sA[128 * 64];
    __shared__ __align__(16) u16 sB[128 * 64];
    f32x4_t acc[4][4];
    const f32x4_t zz = {0.f, 0.f, 0.f, 0.f};
#pragma unroll
    for (int i = 0; i < 4; i++)
#pragma unroll
        for (int j = 0; j < 4; j++) acc[i][j] = zz;

    const int bm = blockIdx.x, bn = blockIdx.y;
    gemm_loop(Ap, W2, 256, bm, bn, sA, sB, acc);

    const int lane = threadIdx.x & 63, wave = threadIdx.x >> 6;
    const int quad = lane >> 4, l16 = lane & 15;
    const int wm = (wave >> 1) * 64, wn = (wave & 1) * 64;
    const int b = bm >> 5;
    const int hw0 = (bm & 31) * 128;
    const int out_f32 = (int)*flag;   // FLIPPED vs round 3: fp32 in -> fp32 out
#pragma unroll
    for (int j = 0; j < 4; j++) {
        int o = bn * 128 + wn + j * 16 + l16;
        float bias = bf2f(b2[o]);
        size_t base = ((size_t)(b * 256 + o)) * 4096;
        if (out_f32) {
            float* Yf = (float*)Y;
#pragma unroll
            for (int i = 0; i < 4; i++) {
                int m0 = hw0 + wm + i * 16 + quad * 4;
                f32x4_t ov;
#pragma unroll
                for (int r = 0; r < 4; r++) ov[r] = acc[i][j][r] + bias;
                *(f32x4_t*)(Yf + base + m0) = ov;
            }
        } else {
            u16* Yh = (u16*)Y;
#pragma unroll
            for (int i = 0; i < 4; i++) {
                int m0 = hw0 + wm + i * 16 + quad * 4;
                u32 lo = (u32)f2bf(acc[i][j][0] + bias) | ((u32)f2bf(acc[i][j][1] + bias) << 16);
                u32 hi = (u32)f2bf(acc[i][j][2] + bias) | ((u32)f2bf(acc[i][j][3] + bias) << 16);
                u32* d32 = (u32*)(Yh + base + m0);
                d32[0] = lo; d32[1] = hi;
            }
        }
    }
}

// ---------------------------------------------------------------------------
extern "C" void kernel_launch(void* const* d_in, const int* in_sizes, int n_in,
                              void* d_out, int out_size, void* d_ws, size_t ws_size,
                              hipStream_t stream) {
    (void)in_sizes; (void)n_in; (void)out_size; (void)ws_size;
    const void* x  = d_in[0];
    const void* W1 = d_in[1];
    const void* b1 = d_in[2];
    const void* W2 = d_in[3];
    const void* b2 = d_in[4];

    char* ws = (char*)d_ws;
    const size_t MB32 = (size_t)32 * 1024 * 1024;
    u16* xT  = (u16*)(ws);              // 32 MB; reused as attention output
    u16* Qp  = (u16*)(ws + MB32);
    u16* Kp  = (u16*)(ws + 2 * MB32);
    u16* Vp  = (u16*)(ws + 3 * MB32);
    u16* W1b = (u16*)(ws + 4 * MB32);   // 196608 elems
    u16* b1b = W1b + 196608;            // 768
    u16* W2b = b1b + 768;               // 65536
    u16* b2b = W2b + 65536;             // 256
    u32* flag = (u32*)(b2b + 256);      // 4 B (aligned)

    detect_k<<<1, 64, 0, stream>>>((const u16*)x, flag);
    conv_w  <<<1028, 256, 0, stream>>>(W1, b1, W2, b2, flag, W1b, b1b, W2b, b2b);
    conv_x  <<<dim3(64, 4, 16), 256, 0, stream>>>(x, flag, xT);
    gemm_qkv<<<dim3(512, 6), 256, 0, stream>>>(xT, W1b, b1b, Qp, Kp, Vp);
    attn_kernel<<<dim3(64, 8, 16), 256, 0, stream>>>(Qp, Kp, Vp, xT);
    gemm_out<<<dim3(512, 2), 256, 0, stream>>>(xT, W2b, b2b, flag, d_out);
}

// Round 5
// 277.902 us; speedup vs baseline: 2.5567x; 2.5567x over previous
//
#include <hip/hip_runtime.h>
#include <stdint.h>

typedef unsigned short u16;
typedef unsigned int   u32;
typedef __bf16 bf16x8_t __attribute__((ext_vector_type(8)));
typedef float  f32x4_t  __attribute__((ext_vector_type(4)));

#define MFMA16(a, b, c) __builtin_amdgcn_mfma_f32_16x16x32_bf16((a), (b), (c), 0, 0, 0)

__device__ __forceinline__ float bf2f(u16 u) {
    union { u32 i; float f; } c; c.i = ((u32)u) << 16; return c.f;
}
__device__ __forceinline__ u16 f2bf(float f) {
    union { float f; u32 i; } c; c.f = f;
    u32 x = c.i;
    return (u16)((x + 0x7fffu + ((x >> 16) & 1u)) >> 16);  // RNE
}

// ---------------------------------------------------------------------------
// Kernel D: detect input dtype (flag=1 -> fp32 inputs, fp32 output).
// ---------------------------------------------------------------------------
__global__ __launch_bounds__(64) void detect_k(const u16* __restrict__ xu,
                                               u32* __restrict__ flag) {
    __shared__ int cnt;
    if (threadIdx.x == 0) cnt = 0;
    __syncthreads();
    int local = 0;
#pragma unroll
    for (int j = 0; j < 4; j++) {
        int i = threadIdx.x * 4 + j;
        u16 w = xu[2 * i];
        int e = (w >> 7) & 0xff;
        if (e >= 80 && e <= 160) local++;
    }
    atomicAdd(&cnt, local);
    __syncthreads();
    if (threadIdx.x == 0) *flag = (cnt < 160) ? 1u : 0u;
}

// ---------------------------------------------------------------------------
// Kernel W: convert W1/b1/W2/b2 to bf16 copies in workspace.
// ---------------------------------------------------------------------------
__global__ __launch_bounds__(256) void conv_w(const void* __restrict__ W1,
                                              const void* __restrict__ b1,
                                              const void* __restrict__ W2,
                                              const void* __restrict__ b2,
                                              const u32* __restrict__ flag,
                                              u16* __restrict__ W1b,
                                              u16* __restrict__ b1b,
                                              u16* __restrict__ W2b,
                                              u16* __restrict__ b2b) {
    int i = blockIdx.x * 256 + threadIdx.x;
    const int n1 = 196608, n2 = 768, n3 = 65536;
    const void* src; u16* dst; int li;
    if (i < n1)                { src = W1; dst = W1b; li = i; }
    else if (i < n1 + n2)      { src = b1; dst = b1b; li = i - n1; }
    else if (i < n1 + n2 + n3) { src = W2; dst = W2b; li = i - n1 - n2; }
    else                       { src = b2; dst = b2b; li = i - n1 - n2 - n3; }
    u16 v;
    if (*flag) v = f2bf(((const float*)src)[li]);
    else       v = ((const u16*)src)[li];
    dst[li] = v;
}

// ---------------------------------------------------------------------------
// Kernel X: x [b][c][hw] -> xT [b*4096+hw][c] bf16 (pixel-major)
// ---------------------------------------------------------------------------
__global__ __launch_bounds__(256) void conv_x(const void* __restrict__ X,
                                              const u32* __restrict__ flag,
                                              u16* __restrict__ XT) {
    __shared__ __align__(16) u16 tile[64][68];
    const int b = blockIdx.z, c0 = blockIdx.y * 64, h0 = blockIdx.x * 64;
    const int tid = threadIdx.x;
    const int col = tid & 63, rq = tid >> 6;
    if (*flag) {
        const float* Xf = (const float*)X;
#pragma unroll
        for (int i = 0; i < 16; i++) {
            int row = i * 4 + rq;
            tile[row][col] = f2bf(Xf[((size_t)(b * 256 + c0 + row)) * 4096 + h0 + col]);
        }
    } else {
        const u16* Xh = (const u16*)X;
#pragma unroll
        for (int i = 0; i < 16; i++) {
            int row = i * 4 + rq;
            tile[row][col] = Xh[((size_t)(b * 256 + c0 + row)) * 4096 + h0 + col];
        }
    }
    __syncthreads();
#pragma unroll
    for (int i = 0; i < 16; i++) {
        int row = i * 4 + rq;
        XT[((size_t)(b * 4096 + h0 + row)) * 256 + c0 + col] = tile[col][row];
    }
}

// ---------------------------------------------------------------------------
// Kernel 1: qkv = xT @ W1^T + b1 with 96-wide n-tiles (= one head exactly).
// Epilogue: LDS roundtrip -> pixel-major per-head Q2/K2/V2 [b][head][hw][e].
// ---------------------------------------------------------------------------
__global__ __launch_bounds__(256) void gemm_qkv(const u16* __restrict__ XT,
                                                const u16* __restrict__ W1,
                                                const u16* __restrict__ b1,
                                                u16* __restrict__ Q2,
                                                u16* __restrict__ K2,
                                                u16* __restrict__ V2) {
    __shared__ __align__(16) u16 smem[128 * 64 + 96 * 64];  // 28 KB
    u16* sA = smem;
    u16* sB = smem + 128 * 64;
    u16* Cs = smem;  // reused after barrier: 128 x 104 = 13312 <= 14336

    const int tid  = threadIdx.x;
    const int lane = tid & 63, wave = tid >> 6;
    const int quad = lane >> 4, l16 = lane & 15;
    const int wm = wave * 32;
    const int bm = blockIdx.x, h = blockIdx.y;
    const int o_base = h * 96;

    f32x4_t acc[2][6];
    const f32x4_t zz = {0.f, 0.f, 0.f, 0.f};
#pragma unroll
    for (int i = 0; i < 2; i++)
#pragma unroll
        for (int j = 0; j < 6; j++) acc[i][j] = zz;

    for (int kt = 0; kt < 256; kt += 64) {
        __syncthreads();
        uint4 av[4], bv[3];
#pragma unroll
        for (int i = 0; i < 4; i++) {
            int idx = i * 256 + tid;
            int row = idx >> 3, cp = idx & 7;
            av[i] = *(const uint4*)(XT + ((size_t)(bm * 128 + row)) * 256 + kt + cp * 8);
        }
#pragma unroll
        for (int i = 0; i < 3; i++) {
            int idx = i * 256 + tid;
            int row = idx >> 3, cp = idx & 7;
            bv[i] = *(const uint4*)(W1 + ((size_t)(o_base + row)) * 256 + kt + cp * 8);
        }
#pragma unroll
        for (int i = 0; i < 4; i++) {
            int idx = i * 256 + tid;
            int row = idx >> 3, cp = idx & 7;
            *(uint4*)(sA + row * 64 + ((cp ^ (row & 7)) * 8)) = av[i];
        }
#pragma unroll
        for (int i = 0; i < 3; i++) {
            int idx = i * 256 + tid;
            int row = idx >> 3, cp = idx & 7;
            *(uint4*)(sB + row * 64 + ((cp ^ (row & 7)) * 8)) = bv[i];
        }
        __syncthreads();
#pragma unroll
        for (int ks = 0; ks < 2; ks++) {
            bf16x8_t af[2], bg[6];
#pragma unroll
            for (int i = 0; i < 2; i++) {
                int row = wm + i * 16 + l16;
                int cp = (ks * 4 + quad) ^ (row & 7);
                af[i] = *(const bf16x8_t*)(sA + row * 64 + cp * 8);
            }
#pragma unroll
            for (int j = 0; j < 6; j++) {
                int row = j * 16 + l16;
                int cp = (ks * 4 + quad) ^ (row & 7);
                bg[j] = *(const bf16x8_t*)(sB + row * 64 + cp * 8);
            }
#pragma unroll
            for (int i = 0; i < 2; i++)
#pragma unroll
                for (int j = 0; j < 6; j++)
                    acc[i][j] = MFMA16(af[i], bg[j], acc[i][j]);
        }
    }

    // ---- epilogue: bias + bf16 -> Cs[128 m][col 96] (stride 104) ----
    __syncthreads();  // all waves done reading sA/sB
#pragma unroll
    for (int j = 0; j < 6; j++) {
        float bias = bf2f(b1[o_base + j * 16 + l16]);
#pragma unroll
        for (int i = 0; i < 2; i++) {
            int m = wm + i * 16 + quad * 4;
#pragma unroll
            for (int r = 0; r < 4; r++)
                Cs[(m + r) * 104 + j * 16 + l16] = f2bf(acc[i][j][r] + bias);
        }
    }
    __syncthreads();

    // ---- repack: col = 3*e + w -> tensor w, pixel-major [b][h][hw][e] ----
    const int b = bm >> 5;
    const int hw0 = (bm & 31) * 128;
    const size_t hb = ((size_t)(b * 8 + h)) * 4096;
#pragma unroll
    for (int it = 0; it < 2; it++) {
        int u = it * 256 + tid;
        int px = u >> 2, ch = u & 3;
        size_t gaddr = (hb + hw0 + px) * 32 + ch * 8;
#pragma unroll
        for (int w = 0; w < 3; w++) {
            u16 vals[8];
#pragma unroll
            for (int jj = 0; jj < 8; jj++)
                vals[jj] = Cs[px * 104 + 3 * (ch * 8 + jj) + w];
            uint4 pk;
            pk.x = (u32)vals[0] | ((u32)vals[1] << 16);
            pk.y = (u32)vals[2] | ((u32)vals[3] << 16);
            pk.z = (u32)vals[4] | ((u32)vals[5] << 16);
            pk.w = (u32)vals[6] | ((u32)vals[7] << 16);
            u16* dst = (w == 0) ? Q2 : (w == 1) ? K2 : V2;
            *(uint4*)(dst + gaddr) = pk;
        }
    }
}

// ---------------------------------------------------------------------------
// Kernel 2: windowed overlapping attention (Q 8x8, K/V 12x12 zero-padded).
// Inputs pixel-major per head [b][head][hw][e] -> fully vectorized staging.
// Output pixel-major [b*4096+hw][c], c = head*32 + e.
// ---------------------------------------------------------------------------
__global__ __launch_bounds__(256) void attn_kernel(const u16* __restrict__ Q2,
                                                   const u16* __restrict__ K2,
                                                   const u16* __restrict__ V2,
                                                   u16* __restrict__ Op) {
    __shared__ __align__(16) u16 Qs[64 * 40];    // [q][e]   stride 40
    __shared__ __align__(16) u16 Ks[144 * 40];   // [k][e]   stride 40
    __shared__ __align__(16) u16 Vt[32 * 168];   // [e][k]   stride 168, cols 144..159 zero
    __shared__ __align__(16) u16 Ps[64 * 168];   // [q][k]   stride 168, cols 144..159 zero

    const int tid  = threadIdx.x;
    const int lane = tid & 63, wave = tid >> 6;
    const int quad = lane >> 4, l16 = lane & 15;
    const int win = blockIdx.x, head = blockIdx.y, b = blockIdx.z;
    const int wi = win >> 3, wj = win & 7;
    const size_t hb = ((size_t)(b * 8 + head)) * 4096;

    // zero the MFMA padding columns (k = 144..159)
    for (int t = tid; t < 64 * 16; t += 256) Ps[(t >> 4) * 168 + 144 + (t & 15)] = 0;
    for (int t = tid; t < 32 * 16; t += 256) Vt[(t >> 4) * 168 + 144 + (t & 15)] = 0;

    // ---- stage Q: 64 px x 4 chunks, all-vector ----
    {
        int px = tid >> 2, ch = tid & 3;
        int qy = px >> 3, qx = px & 7;
        uint4 v = *(const uint4*)(Q2 + (hb + (wi * 8 + qy) * 64 + wj * 8 + qx) * 32 + ch * 8);
        *(uint4*)(Qs + px * 40 + ch * 8) = v;
    }
    // ---- stage K: 144 px x 4 chunks ----
    for (int u = tid; u < 576; u += 256) {
        int px = u >> 2, ch = u & 3;
        int py = px / 12, kx = px - py * 12;
        int gy = wi * 8 - 2 + py, gx = wj * 8 - 2 + kx;
        uint4 v = make_uint4(0, 0, 0, 0);
        if (gy >= 0 && gy < 64 && gx >= 0 && gx < 64)
            v = *(const uint4*)(K2 + (hb + gy * 64 + gx) * 32 + ch * 8);
        *(uint4*)(Ks + px * 40 + ch * 8) = v;
    }
    // ---- stage V transposed: vector load, scalar LDS transpose ----
    for (int u = tid; u < 576; u += 256) {
        int px = u >> 2, ch = u & 3;
        int py = px / 12, kx = px - py * 12;
        int gy = wi * 8 - 2 + py, gx = wj * 8 - 2 + kx;
        uint4 v = make_uint4(0, 0, 0, 0);
        if (gy >= 0 && gy < 64 && gx >= 0 && gx < 64)
            v = *(const uint4*)(V2 + (hb + gy * 64 + gx) * 32 + ch * 8);
        int e0 = ch * 8;
        u32 vv[4] = {v.x, v.y, v.z, v.w};
#pragma unroll
        for (int p = 0; p < 4; p++) {
            Vt[(e0 + 2 * p    ) * 168 + px] = (u16)(vv[p] & 0xffff);
            Vt[(e0 + 2 * p + 1) * 168 + px] = (u16)(vv[p] >> 16);
        }
    }
    __syncthreads();

    // ---- scores: S = Q K^T * scale (wave w owns q rows 16w..16w+15) ----
    const float scale = 0.17677669529663687f;  // 1/sqrt(32)
    float s[9][4];
    {
        bf16x8_t aF = *(const bf16x8_t*)(Qs + (wave * 16 + l16) * 40 + quad * 8);
        const f32x4_t zz = {0.f, 0.f, 0.f, 0.f};
#pragma unroll
        for (int j = 0; j < 9; j++) {
            bf16x8_t bF = *(const bf16x8_t*)(Ks + (j * 16 + l16) * 40 + quad * 8);
            f32x4_t d = MFMA16(aF, bF, zz);
#pragma unroll
            for (int r = 0; r < 4; r++) s[j][r] = d[r] * scale;
        }
    }
    // ---- softmax (rows = quad*4 + r, reduce over 16 lanes) ----
    float mx[4] = {-1e30f, -1e30f, -1e30f, -1e30f};
#pragma unroll
    for (int j = 0; j < 9; j++)
#pragma unroll
        for (int r = 0; r < 4; r++) mx[r] = fmaxf(mx[r], s[j][r]);
#pragma unroll
    for (int off = 1; off < 16; off <<= 1)
#pragma unroll
        for (int r = 0; r < 4; r++) mx[r] = fmaxf(mx[r], __shfl_xor(mx[r], off, 16));

    float sm[4] = {0.f, 0.f, 0.f, 0.f};
#pragma unroll
    for (int j = 0; j < 9; j++) {
#pragma unroll
        for (int r = 0; r < 4; r++) {
            float p = __expf(fminf(s[j][r] - mx[r], 0.f));
            u16 pb = f2bf(p);
            sm[r] += bf2f(pb);
            Ps[(wave * 16 + quad * 4 + r) * 168 + j * 16 + l16] = pb;
        }
    }
#pragma unroll
    for (int off = 1; off < 16; off <<= 1)
#pragma unroll
        for (int r = 0; r < 4; r++) sm[r] += __shfl_xor(sm[r], off, 16);

    __syncthreads();  // fence Ps u16 stores vs bf16x8 loads

    // ---- O = P V (K-dim padded to 160 with zeros) ----
    f32x4_t oa[2];
    oa[0] = (f32x4_t){0.f, 0.f, 0.f, 0.f};
    oa[1] = (f32x4_t){0.f, 0.f, 0.f, 0.f};
#pragma unroll
    for (int kk = 0; kk < 5; kk++) {
        bf16x8_t aP = *(const bf16x8_t*)(Ps + (wave * 16 + l16) * 168 + kk * 32 + quad * 8);
#pragma unroll
        for (int nt = 0; nt < 2; nt++) {
            bf16x8_t bV = *(const bf16x8_t*)(Vt + (nt * 16 + l16) * 168 + kk * 32 + quad * 8);
            oa[nt] = MFMA16(aP, bV, oa[nt]);
        }
    }
    float inv[4];
#pragma unroll
    for (int r = 0; r < 4; r++) inv[r] = 1.0f / fmaxf(sm[r], 1e-20f);
#pragma unroll
    for (int nt = 0; nt < 2; nt++) {
        int e = nt * 16 + l16;
#pragma unroll
        for (int r = 0; r < 4; r++) {
            int q = wave * 16 + quad * 4 + r;
            int qy = q >> 3, qx = q & 7;
            size_t pix = (size_t)(b * 4096) + (wi * 8 + qy) * 64 + (wj * 8 + qx);
            Op[pix * 256 + head * 32 + e] = f2bf(oa[nt][r] * inv[r]);
        }
    }
}

// ---------------------------------------------------------------------------
// Shared 128x128 GEMM mainloop (used by gemm_out).
// ---------------------------------------------------------------------------
__device__ __forceinline__ void gemm_loop(const u16* __restrict__ A,
                                          const u16* __restrict__ B,
                                          int K, int bm, int bn,
                                          u16* sA, u16* sB, f32x4_t acc[4][4]) {
    const int tid  = threadIdx.x;
    const int lane = tid & 63, wave = tid >> 6;
    const int quad = lane >> 4, l16 = lane & 15;
    const int wm = (wave >> 1) * 64, wn = (wave & 1) * 64;

    for (int kt = 0; kt < K; kt += 64) {
        __syncthreads();
        uint4 av[4], bv[4];
#pragma unroll
        for (int i = 0; i < 4; i++) {
            int idx = i * 256 + tid;
            int row = idx >> 3, cp = idx & 7;
            av[i] = *(const uint4*)(A + ((size_t)(bm * 128 + row)) * K + kt + cp * 8);
            bv[i] = *(const uint4*)(B + ((size_t)(bn * 128 + row)) * K + kt + cp * 8);
        }
#pragma unroll
        for (int i = 0; i < 4; i++) {
            int idx = i * 256 + tid;
            int row = idx >> 3, cp = idx & 7;
            int sp = row * 64 + ((cp ^ (row & 7)) * 8);
            *(uint4*)(sA + sp) = av[i];
            *(uint4*)(sB + sp) = bv[i];
        }
        __syncthreads();
#pragma unroll
        for (int ks = 0; ks < 2; ks++) {
            bf16x8_t af[4], bg[4];
#pragma unroll
            for (int i = 0; i < 4; i++) {
                int row = wm + i * 16 + l16;
                int cp = (ks * 4 + quad) ^ (row & 7);
                af[i] = *(const bf16x8_t*)(sA + row * 64 + cp * 8);
            }
#pragma unroll
            for (int j = 0; j < 4; j++) {
                int row = wn + j * 16 + l16;
                int cp = (ks * 4 + quad) ^ (row & 7);
                bg[j] = *(const bf16x8_t*)(sB + row * 64 + cp * 8);
            }
#pragma unroll
            for (int i = 0; i < 4; i++)
#pragma unroll
                for (int j = 0; j < 4; j++)
                    acc[i][j] = MFMA16(af[i], bg[j], acc[i][j]);
        }
    }
}

// ---------------------------------------------------------------------------
// Kernel 3: y = attn @ W2^T + b2 -> d_out [b][c'][hw]; fp32 if flag else bf16.
// ---------------------------------------------------------------------------
__global__ __launch_bounds__(256) void gemm_out(const u16* __restrict__ Ap,
                                                const u16* __restrict__ W2,
                                                const u16* __restrict__ b2,
                                                const u32* __restrict__ flag,
                                                void* __restrict__ Y) {
    __shared__ __align__(16) u16 sA[128 * 64];
    __shared__ __align__(16) u16 sB[128 * 64];
    f32x4_t acc[4][4];
    const f32x4_t zz = {0.f, 0.f, 0.f, 0.f};
#pragma unroll
    for (int i = 0; i < 4; i++)
#pragma unroll
        for (int j = 0; j < 4; j++) acc[i][j] = zz;

    const int bm = blockIdx.x, bn = blockIdx.y;
    gemm_loop(Ap, W2, 256, bm, bn, sA, sB, acc);

    const int lane = threadIdx.x & 63, wave = threadIdx.x >> 6;
    const int quad = lane >> 4, l16 = lane & 15;
    const int wm = (wave >> 1) * 64, wn = (wave & 1) * 64;
    const int b = bm >> 5;
    const int hw0 = (bm & 31) * 128;
    const int out_f32 = (int)*flag;
#pragma unroll
    for (int j = 0; j < 4; j++) {
        int o = bn * 128 + wn + j * 16 + l16;
        float bias = bf2f(b2[o]);
        size_t base = ((size_t)(b * 256 + o)) * 4096;
        if (out_f32) {
            float* Yf = (float*)Y;
#pragma unroll
            for (int i = 0; i < 4; i++) {
                int m0 = hw0 + wm + i * 16 + quad * 4;
                f32x4_t ov;
#pragma unroll
                for (int r = 0; r < 4; r++) ov[r] = acc[i][j][r] + bias;
                *(f32x4_t*)(Yf + base + m0) = ov;
            }
        } else {
            u16* Yh = (u16*)Y;
#pragma unroll
            for (int i = 0; i < 4; i++) {
                int m0 = hw0 + wm + i * 16 + quad * 4;
                u32 lo = (u32)f2bf(acc[i][j][0] + bias) | ((u32)f2bf(acc[i][j][1] + bias) << 16);
                u32 hi = (u32)f2bf(acc[i][j][2] + bias) | ((u32)f2bf(acc[i][j][3] + bias) << 16);
                u32* d32 = (u32*)(Yh + base + m0);
                d32[0] = lo; d32[1] = hi;
            }
        }
    }
}

// ---------------------------------------------------------------------------
extern "C" void kernel_launch(void* const* d_in, const int* in_sizes, int n_in,
                              void* d_out, int out_size, void* d_ws, size_t ws_size,
                              hipStream_t stream) {
    (void)in_sizes; (void)n_in; (void)out_size; (void)ws_size;
    const void* x  = d_in[0];
    const void* W1 = d_in[1];
    const void* b1 = d_in[2];
    const void* W2 = d_in[3];
    const void* b2 = d_in[4];

    char* ws = (char*)d_ws;
    const size_t MB32 = (size_t)32 * 1024 * 1024;
    u16* xT  = (u16*)(ws);              // 32 MiB; reused as attention output Op
    u16* Q2  = (u16*)(ws + MB32);       // 32 MiB  [b][head][hw][e]
    u16* K2  = (u16*)(ws + 2 * MB32);   // 32 MiB
    u16* V2  = (u16*)(ws + 3 * MB32);   // 32 MiB
    u16* W1b = (u16*)(ws + 4 * MB32);   // 196608 elems
    u16* b1b = W1b + 196608;            // 768
    u16* W2b = b1b + 768;               // 65536
    u16* b2b = W2b + 65536;             // 256
    u32* flag = (u32*)(b2b + 256);      // 4 B
    u16* Op  = xT;                      // overlay: xT dead after gemm_qkv

    detect_k<<<1, 64, 0, stream>>>((const u16*)x, flag);
    conv_w  <<<1028, 256, 0, stream>>>(W1, b1, W2, b2, flag, W1b, b1b, W2b, b2b);
    conv_x  <<<dim3(64, 4, 16), 256, 0, stream>>>(x, flag, xT);
    gemm_qkv<<<dim3(512, 8), 256, 0, stream>>>(xT, W1b, b1b, Q2, K2, V2);
    attn_kernel<<<dim3(64, 8, 16), 256, 0, stream>>>(Q2, K2, V2, Op);
    gemm_out<<<dim3(512, 2), 256, 0, stream>>>(Op, W2b, b2b, flag, d_out);
}

// Round 6
// 242.730 us; speedup vs baseline: 2.9272x; 1.1449x over previous
//
#include <hip/hip_runtime.h>
#include <stdint.h>

typedef unsigned short u16;
typedef unsigned int   u32;
typedef __bf16 bf16x8_t __attribute__((ext_vector_type(8)));
typedef float  f32x4_t  __attribute__((ext_vector_type(4)));

#define MFMA16(a, b, c) __builtin_amdgcn_mfma_f32_16x16x32_bf16((a), (b), (c), 0, 0, 0)

__device__ __forceinline__ float bf2f(u16 u) {
    union { u32 i; float f; } c; c.i = ((u32)u) << 16; return c.f;
}
__device__ __forceinline__ u16 f2bf(float f) {
    union { float f; u32 i; } c; c.f = f;
    u32 x = c.i;
    return (u16)((x + 0x7fffu + ((x >> 16) & 1u)) >> 16);  // RNE
}

// ---------------------------------------------------------------------------
// Block-local input-dtype detection (flag=1 -> fp32 inputs). Even u16 halves
// of fp32 data have ~32% "sane" bf16 exponents; real bf16 data ~100%.
// Deterministic, same work every call; 256-thread blocks only.
// ---------------------------------------------------------------------------
__device__ __forceinline__ u32 detect_fp32(const u16* __restrict__ xu,
                                           int tid, int* wcnt) {
    u16 w = xu[2 * tid];
    int e = (w >> 7) & 0xff;
    int ok = (e >= 80 && e <= 160) ? 1 : 0;
    unsigned long long m = __ballot(ok);
    if ((tid & 63) == 0) wcnt[tid >> 6] = __popcll(m);
    __syncthreads();
    int cnt = wcnt[0] + wcnt[1] + wcnt[2] + wcnt[3];
    return (cnt < 160) ? 1u : 0u;
}

// ---------------------------------------------------------------------------
// Kernel W: convert W1/b1/W2/b2 to bf16 copies in workspace.
// ---------------------------------------------------------------------------
__global__ __launch_bounds__(256) void conv_w(const u16* __restrict__ xu,
                                              const void* __restrict__ W1,
                                              const void* __restrict__ b1,
                                              const void* __restrict__ W2,
                                              const void* __restrict__ b2,
                                              u16* __restrict__ W1b,
                                              u16* __restrict__ b1b,
                                              u16* __restrict__ W2b,
                                              u16* __restrict__ b2b) {
    __shared__ int wcnt[4];
    u32 f = detect_fp32(xu, threadIdx.x, wcnt);
    int i = blockIdx.x * 256 + threadIdx.x;
    const int n1 = 196608, n2 = 768, n3 = 65536;
    const void* src; u16* dst; int li;
    if (i < n1)                { src = W1; dst = W1b; li = i; }
    else if (i < n1 + n2)      { src = b1; dst = b1b; li = i - n1; }
    else if (i < n1 + n2 + n3) { src = W2; dst = W2b; li = i - n1 - n2; }
    else                       { src = b2; dst = b2b; li = i - n1 - n2 - n3; }
    u16 v;
    if (f) v = f2bf(((const float*)src)[li]);
    else   v = ((const u16*)src)[li];
    dst[li] = v;
}

// ---------------------------------------------------------------------------
// Kernel X: x [b][c][hw] -> xT [b*4096+hw][c] bf16 (pixel-major)
// ---------------------------------------------------------------------------
__global__ __launch_bounds__(256) void conv_x(const void* __restrict__ X,
                                              u16* __restrict__ XT) {
    __shared__ __align__(16) u16 tile[64][68];
    __shared__ int wcnt[4];
    const int tid = threadIdx.x;
    u32 f = detect_fp32((const u16*)X, tid, wcnt);
    const int b = blockIdx.z, c0 = blockIdx.y * 64, h0 = blockIdx.x * 64;
    const int col = tid & 63, rq = tid >> 6;
    if (f) {
        const float* Xf = (const float*)X;
#pragma unroll
        for (int i = 0; i < 16; i++) {
            int row = i * 4 + rq;
            tile[row][col] = f2bf(Xf[((size_t)(b * 256 + c0 + row)) * 4096 + h0 + col]);
        }
    } else {
        const u16* Xh = (const u16*)X;
#pragma unroll
        for (int i = 0; i < 16; i++) {
            int row = i * 4 + rq;
            tile[row][col] = Xh[((size_t)(b * 256 + c0 + row)) * 4096 + h0 + col];
        }
    }
    __syncthreads();
#pragma unroll
    for (int i = 0; i < 16; i++) {
        int row = i * 4 + rq;
        XT[((size_t)(b * 4096 + h0 + row)) * 256 + c0 + col] = tile[col][row];
    }
}

// ---------------------------------------------------------------------------
// Kernel 1: qkv = xT @ W1^T + b1 with 96-wide n-tiles (= one head exactly).
// Block swizzle: the 8 head-blocks sharing an A-tile are 8 ids apart -> same
// XCD (id%8 heuristic) and temporally adjacent -> A-tile re-reads hit L2.
// Epilogue: LDS roundtrip -> pixel-major per-head Q2/K2/V2 [b][head][hw][e].
// ---------------------------------------------------------------------------
__global__ __launch_bounds__(256) void gemm_qkv(const u16* __restrict__ XT,
                                                const u16* __restrict__ W1,
                                                const u16* __restrict__ b1,
                                                u16* __restrict__ Q2,
                                                u16* __restrict__ K2,
                                                u16* __restrict__ V2) {
    __shared__ __align__(16) u16 smem[128 * 64 + 96 * 64];  // 28 KB
    u16* sA = smem;
    u16* sB = smem + 128 * 64;
    u16* Cs = smem;  // reused after barrier: 128 x 104 = 13312 <= 14336

    const int tid  = threadIdx.x;
    const int lane = tid & 63, wave = tid >> 6;
    const int quad = lane >> 4, l16 = lane & 15;
    const int wm = wave * 32;
    const int bx = blockIdx.x;
    const int bm = (bx >> 6) * 8 + (bx & 7);  // 512 m-tiles
    const int h  = (bx >> 3) & 7;             // 8 heads
    const int o_base = h * 96;

    f32x4_t acc[2][6];
    const f32x4_t zz = {0.f, 0.f, 0.f, 0.f};
#pragma unroll
    for (int i = 0; i < 2; i++)
#pragma unroll
        for (int j = 0; j < 6; j++) acc[i][j] = zz;

    for (int kt = 0; kt < 256; kt += 64) {
        __syncthreads();
        uint4 av[4], bv[3];
#pragma unroll
        for (int i = 0; i < 4; i++) {
            int idx = i * 256 + tid;
            int row = idx >> 3, cp = idx & 7;
            av[i] = *(const uint4*)(XT + ((size_t)(bm * 128 + row)) * 256 + kt + cp * 8);
        }
#pragma unroll
        for (int i = 0; i < 3; i++) {
            int idx = i * 256 + tid;
            int row = idx >> 3, cp = idx & 7;
            bv[i] = *(const uint4*)(W1 + ((size_t)(o_base + row)) * 256 + kt + cp * 8);
        }
#pragma unroll
        for (int i = 0; i < 4; i++) {
            int idx = i * 256 + tid;
            int row = idx >> 3, cp = idx & 7;
            *(uint4*)(sA + row * 64 + ((cp ^ (row & 7)) * 8)) = av[i];
        }
#pragma unroll
        for (int i = 0; i < 3; i++) {
            int idx = i * 256 + tid;
            int row = idx >> 3, cp = idx & 7;
            *(uint4*)(sB + row * 64 + ((cp ^ (row & 7)) * 8)) = bv[i];
        }
        __syncthreads();
#pragma unroll
        for (int ks = 0; ks < 2; ks++) {
            bf16x8_t af[2], bg[6];
#pragma unroll
            for (int i = 0; i < 2; i++) {
                int row = wm + i * 16 + l16;
                int cp = (ks * 4 + quad) ^ (row & 7);
                af[i] = *(const bf16x8_t*)(sA + row * 64 + cp * 8);
            }
#pragma unroll
            for (int j = 0; j < 6; j++) {
                int row = j * 16 + l16;
                int cp = (ks * 4 + quad) ^ (row & 7);
                bg[j] = *(const bf16x8_t*)(sB + row * 64 + cp * 8);
            }
#pragma unroll
            for (int i = 0; i < 2; i++)
#pragma unroll
                for (int j = 0; j < 6; j++)
                    acc[i][j] = MFMA16(af[i], bg[j], acc[i][j]);
        }
    }

    // ---- epilogue: bias + bf16 -> Cs[128 m][col 96] (stride 104) ----
    __syncthreads();
#pragma unroll
    for (int j = 0; j < 6; j++) {
        float bias = bf2f(b1[o_base + j * 16 + l16]);
#pragma unroll
        for (int i = 0; i < 2; i++) {
            int m = wm + i * 16 + quad * 4;
#pragma unroll
            for (int r = 0; r < 4; r++)
                Cs[(m + r) * 104 + j * 16 + l16] = f2bf(acc[i][j][r] + bias);
        }
    }
    __syncthreads();

    // ---- repack: col = 3*e + w -> tensor w, pixel-major [b][h][hw][e] ----
    const int b = bm >> 5;
    const int hw0 = (bm & 31) * 128;
    const size_t hb = ((size_t)(b * 8 + h)) * 4096;
#pragma unroll
    for (int it = 0; it < 2; it++) {
        int u = it * 256 + tid;
        int px = u >> 2, ch = u & 3;
        size_t gaddr = (hb + hw0 + px) * 32 + ch * 8;
#pragma unroll
        for (int w = 0; w < 3; w++) {
            u16 vals[8];
#pragma unroll
            for (int jj = 0; jj < 8; jj++)
                vals[jj] = Cs[px * 104 + 3 * (ch * 8 + jj) + w];
            uint4 pk;
            pk.x = (u32)vals[0] | ((u32)vals[1] << 16);
            pk.y = (u32)vals[2] | ((u32)vals[3] << 16);
            pk.z = (u32)vals[4] | ((u32)vals[5] << 16);
            pk.w = (u32)vals[6] | ((u32)vals[7] << 16);
            u16* dst = (w == 0) ? Q2 : (w == 1) ? K2 : V2;
            *(uint4*)(dst + gaddr) = pk;
        }
    }
}

// ---------------------------------------------------------------------------
// Kernel 2: windowed overlapping attention (Q 8x8, K/V 12x12 zero-padded).
// LDS plan (37.4 KB -> 4 blocks/CU):
//   Qs   [64][40]               5120 B
//   Ks   [144][40] ... overlaid by Ps [64][168] after QK^T   21504 B
//   Vt   [32][168] XOR-swizzled cols (conflict-free transpose) 10752 B
// Vt swizzle: phys_col = log_col ^ ((e>>3)<<3) — bijection on [0,160),
// keeps 8-blocks contiguous (b128-safe), distributes the 4 writer lanes
// (e0 = 0,8,16,24 at same px) onto 4 distinct banks.
// ---------------------------------------------------------------------------
__global__ __launch_bounds__(256) void attn_kernel(const u16* __restrict__ Q2,
                                                   const u16* __restrict__ K2,
                                                   const u16* __restrict__ V2,
                                                   u16* __restrict__ Op) {
    __shared__ __align__(16) u16 smem[18688];
    u16* Qs = smem;               // [q][e]    stride 40
    u16* Ks = smem + 2560;        // [k][e]    stride 40   (dead after QK^T)
    u16* Ps = Ks;                 // [q][k]    stride 168  (overlay)
    u16* Vt = smem + 13312;       // [e][k]    stride 168, swizzled cols

    const int tid  = threadIdx.x;
    const int lane = tid & 63, wave = tid >> 6;
    const int quad = lane >> 4, l16 = lane & 15;
    const int win = blockIdx.x, head = blockIdx.y, b = blockIdx.z;
    const int wi = win >> 3, wj = win & 7;
    const size_t hb = ((size_t)(b * 8 + head)) * 4096;

    // ---- stage Q: 64 px x 4 chunks, all-vector ----
    {
        int px = tid >> 2, ch = tid & 3;
        int qy = px >> 3, qx = px & 7;
        uint4 v = *(const uint4*)(Q2 + (hb + (wi * 8 + qy) * 64 + wj * 8 + qx) * 32 + ch * 8);
        *(uint4*)(Qs + px * 40 + ch * 8) = v;
    }
    // ---- stage K + V (merged, one addr calc); V transposed w/ swizzle ----
    for (int u = tid; u < 576; u += 256) {
        int px = u >> 2, ch = u & 3;
        int py = px / 12, kx = px - py * 12;
        int gy = wi * 8 - 2 + py, gx = wj * 8 - 2 + kx;
        uint4 kv = make_uint4(0, 0, 0, 0), vv = make_uint4(0, 0, 0, 0);
        if (gy >= 0 && gy < 64 && gx >= 0 && gx < 64) {
            size_t off = (hb + gy * 64 + gx) * 32 + ch * 8;
            kv = *(const uint4*)(K2 + off);
            vv = *(const uint4*)(V2 + off);
        }
        *(uint4*)(Ks + px * 40 + ch * 8) = kv;
        int colp = px ^ (ch << 3);
        int e0 = ch * 8;
        u32 w0[4] = {vv.x, vv.y, vv.z, vv.w};
#pragma unroll
        for (int p = 0; p < 4; p++) {
            Vt[(e0 + 2 * p    ) * 168 + colp] = (u16)(w0[p] & 0xffff);
            Vt[(e0 + 2 * p + 1) * 168 + colp] = (u16)(w0[p] >> 16);
        }
    }
    // ---- Vt pad cols 144..159 (swizzled addresses) ----
    for (int t = tid; t < 512; t += 256) {
        int e = t >> 4, cl = 144 + (t & 15);
        Vt[e * 168 + (cl ^ ((e >> 3) << 3))] = 0;
    }
    __syncthreads();

    // ---- scores: S_raw = Q K^T (wave w owns q rows 16w..16w+15) ----
    float s[9][4];
    {
        bf16x8_t aF = *(const bf16x8_t*)(Qs + (wave * 16 + l16) * 40 + quad * 8);
        const f32x4_t zz = {0.f, 0.f, 0.f, 0.f};
#pragma unroll
        for (int j = 0; j < 9; j++) {
            bf16x8_t bF = *(const bf16x8_t*)(Ks + (j * 16 + l16) * 40 + quad * 8);
            f32x4_t d = MFMA16(aF, bF, zz);
#pragma unroll
            for (int r = 0; r < 4; r++) s[j][r] = d[r];
        }
    }
    // ---- row max on raw scores (scale folded into exp arg) ----
    float mx[4] = {-1e30f, -1e30f, -1e30f, -1e30f};
#pragma unroll
    for (int j = 0; j < 9; j++)
#pragma unroll
        for (int r = 0; r < 4; r++) mx[r] = fmaxf(mx[r], s[j][r]);
#pragma unroll
    for (int off = 1; off < 16; off <<= 1)
#pragma unroll
        for (int r = 0; r < 4; r++) mx[r] = fmaxf(mx[r], __shfl_xor(mx[r], off, 16));

    __syncthreads();  // Ks fully consumed by all waves; Ps overlay begins

    // ---- Ps pad cols 144..159 for this wave's 16 rows (one b64/lane) ----
    *(unsigned long long*)(Ps + (wave * 16 + l16) * 168 + 144 + quad * 4) = 0ULL;

    const float scale = 0.17677669529663687f;  // 1/sqrt(32)
    float sm[4] = {0.f, 0.f, 0.f, 0.f};
#pragma unroll
    for (int j = 0; j < 9; j++) {
#pragma unroll
        for (int r = 0; r < 4; r++) {
            float p = __expf((s[j][r] - mx[r]) * scale);
            sm[r] += p;
            Ps[(wave * 16 + quad * 4 + r) * 168 + j * 16 + l16] = f2bf(p);
        }
    }
#pragma unroll
    for (int off = 1; off < 16; off <<= 1)
#pragma unroll
        for (int r = 0; r < 4; r++) sm[r] += __shfl_xor(sm[r], off, 16);

    __syncthreads();  // fence Ps u16 stores vs bf16x8 loads (all waves)

    // ---- O = P V (K-dim padded to 160 with zeros) ----
    f32x4_t oa[2];
    oa[0] = (f32x4_t){0.f, 0.f, 0.f, 0.f};
    oa[1] = (f32x4_t){0.f, 0.f, 0.f, 0.f};
#pragma unroll
    for (int kk = 0; kk < 5; kk++) {
        bf16x8_t aP = *(const bf16x8_t*)(Ps + (wave * 16 + l16) * 168 + kk * 32 + quad * 8);
#pragma unroll
        for (int nt = 0; nt < 2; nt++) {
            int er = nt * 16 + l16;
            int sw = (er >> 3) << 3;
            bf16x8_t bV = *(const bf16x8_t*)(Vt + er * 168 + ((kk * 32 + quad * 8) ^ sw));
            oa[nt] = MFMA16(aP, bV, oa[nt]);
        }
    }
    float inv[4];
#pragma unroll
    for (int r = 0; r < 4; r++) inv[r] = 1.0f / sm[r];  // sm >= 1 (max term)
#pragma unroll
    for (int nt = 0; nt < 2; nt++) {
        int e = nt * 16 + l16;
#pragma unroll
        for (int r = 0; r < 4; r++) {
            int q = wave * 16 + quad * 4 + r;
            int qy = q >> 3, qx = q & 7;
            size_t pix = (size_t)(b * 4096) + (wi * 8 + qy) * 64 + (wj * 8 + qx);
            Op[pix * 256 + head * 32 + e] = f2bf(oa[nt][r] * inv[r]);
        }
    }
}

// ---------------------------------------------------------------------------
// Shared 128x128 GEMM mainloop (used by gemm_out).
// ---------------------------------------------------------------------------
__device__ __forceinline__ void gemm_loop(const u16* __restrict__ A,
                                          const u16* __restrict__ B,
                                          int K, int bm, int bn,
                                          u16* sA, u16* sB, f32x4_t acc[4][4]) {
    const int tid  = threadIdx.x;
    const int lane = tid & 63, wave = tid >> 6;
    const int quad = lane >> 4, l16 = lane & 15;
    const int wm = (wave >> 1) * 64, wn = (wave & 1) * 64;

    for (int kt = 0; kt < K; kt += 64) {
        __syncthreads();
        uint4 av[4], bv[4];
#pragma unroll
        for (int i = 0; i < 4; i++) {
            int idx = i * 256 + tid;
            int row = idx >> 3, cp = idx & 7;
            av[i] = *(const uint4*)(A + ((size_t)(bm * 128 + row)) * K + kt + cp * 8);
            bv[i] = *(const uint4*)(B + ((size_t)(bn * 128 + row)) * K + kt + cp * 8);
        }
#pragma unroll
        for (int i = 0; i < 4; i++) {
            int idx = i * 256 + tid;
            int row = idx >> 3, cp = idx & 7;
            int sp = row * 64 + ((cp ^ (row & 7)) * 8);
            *(uint4*)(sA + sp) = av[i];
            *(uint4*)(sB + sp) = bv[i];
        }
        __syncthreads();
#pragma unroll
        for (int ks = 0; ks < 2; ks++) {
            bf16x8_t af[4], bg[4];
#pragma unroll
            for (int i = 0; i < 4; i++) {
                int row = wm + i * 16 + l16;
                int cp = (ks * 4 + quad) ^ (row & 7);
                af[i] = *(const bf16x8_t*)(sA + row * 64 + cp * 8);
            }
#pragma unroll
            for (int j = 0; j < 4; j++) {
                int row = wn + j * 16 + l16;
                int cp = (ks * 4 + quad) ^ (row & 7);
                bg[j] = *(const bf16x8_t*)(sB + row * 64 + cp * 8);
            }
#pragma unroll
            for (int i = 0; i < 4; i++)
#pragma unroll
                for (int j = 0; j < 4; j++)
                    acc[i][j] = MFMA16(af[i], bg[j], acc[i][j]);
        }
    }
}

// ---------------------------------------------------------------------------
// Kernel 3: y = attn @ W2^T + b2 -> d_out [b][c'][hw]; fp32 if fp32 inputs.
// ---------------------------------------------------------------------------
__global__ __launch_bounds__(256) void gemm_out(const u16* __restrict__ xu,
                                                const u16* __restrict__ Ap,
                                                const u16* __restrict__ W2,
                                                const u16* __restrict__ b2,
                                                void* __restrict__ Y) {
    __shared__ __align__(16) u16 sA[128 * 64];
    __shared__ __align__(16) u16 sB[128 * 64];
    __shared__ int wcnt[4];
    const u32 out_f32 = detect_fp32(xu, threadIdx.x, wcnt);

    f32x4_t acc[4][4];
    const f32x4_t zz = {0.f, 0.f, 0.f, 0.f};
#pragma unroll
    for (int i = 0; i < 4; i++)
#pragma unroll
        for (int j = 0; j < 4; j++) acc[i][j] = zz;

    const int bm = blockIdx.x, bn = blockIdx.y;
    gemm_loop(Ap, W2, 256, bm, bn, sA, sB, acc);

    const int lane = threadIdx.x & 63, wave = threadIdx.x >> 6;
    const int quad = lane >> 4, l16 = lane & 15;
    const int wm = (wave >> 1) * 64, wn = (wave & 1) * 64;
    const int b = bm >> 5;
    const int hw0 = (bm & 31) * 128;
#pragma unroll
    for (int j = 0; j < 4; j++) {
        int o = bn * 128 + wn + j * 16 + l16;
        float bias = bf2f(b2[o]);
        size_t base = ((size_t)(b * 256 + o)) * 4096;
        if (out_f32) {
            float* Yf = (float*)Y;
#pragma unroll
            for (int i = 0; i < 4; i++) {
                int m0 = hw0 + wm + i * 16 + quad * 4;
                f32x4_t ov;
#pragma unroll
                for (int r = 0; r < 4; r++) ov[r] = acc[i][j][r] + bias;
                *(f32x4_t*)(Yf + base + m0) = ov;
            }
        } else {
            u16* Yh = (u16*)Y;
#pragma unroll
            for (int i = 0; i < 4; i++) {
                int m0 = hw0 + wm + i * 16 + quad * 4;
                u32 lo = (u32)f2bf(acc[i][j][0] + bias) | ((u32)f2bf(acc[i][j][1] + bias) << 16);
                u32 hi = (u32)f2bf(acc[i][j][2] + bias) | ((u32)f2bf(acc[i][j][3] + bias) << 16);
                u32* d32 = (u32*)(Yh + base + m0);
                d32[0] = lo; d32[1] = hi;
            }
        }
    }
}

// ---------------------------------------------------------------------------
extern "C" void kernel_launch(void* const* d_in, const int* in_sizes, int n_in,
                              void* d_out, int out_size, void* d_ws, size_t ws_size,
                              hipStream_t stream) {
    (void)in_sizes; (void)n_in; (void)out_size; (void)ws_size;
    const void* x  = d_in[0];
    const void* W1 = d_in[1];
    const void* b1 = d_in[2];
    const void* W2 = d_in[3];
    const void* b2 = d_in[4];
    const u16* xu = (const u16*)x;

    char* ws = (char*)d_ws;
    const size_t MB32 = (size_t)32 * 1024 * 1024;
    u16* xT  = (u16*)(ws);              // 32 MiB; reused as attention output Op
    u16* Q2  = (u16*)(ws + MB32);       // 32 MiB  [b][head][hw][e]
    u16* K2  = (u16*)(ws + 2 * MB32);   // 32 MiB
    u16* V2  = (u16*)(ws + 3 * MB32);   // 32 MiB
    u16* W1b = (u16*)(ws + 4 * MB32);   // 196608 elems
    u16* b1b = W1b + 196608;            // 768
    u16* W2b = b1b + 768;               // 65536
    u16* b2b = W2b + 65536;             // 256
    u16* Op  = xT;                      // overlay: xT dead after gemm_qkv

    conv_w  <<<1028, 256, 0, stream>>>(xu, W1, b1, W2, b2, W1b, b1b, W2b, b2b);
    conv_x  <<<dim3(64, 4, 16), 256, 0, stream>>>(x, xT);
    gemm_qkv<<<4096, 256, 0, stream>>>(xT, W1b, b1b, Q2, K2, V2);
    attn_kernel<<<dim3(64, 8, 16), 256, 0, stream>>>(Q2, K2, V2, Op);
    gemm_out<<<dim3(512, 2), 256, 0, stream>>>(xu, Op, W2b, b2b, d_out);
}